// Round 16
// baseline (107.046 us; speedup 1.0000x reference)
//
#include <hip/hip_runtime.h>

// LangNN via 16x16x32 bf16 MFMA. B=131072, H=25, A=18.
// Round-16: PRODUCER/CONSUMER WAVE SPECIALIZATION. Waves 0-3 = encoder
// (32 rows each as 2 M-tiles), waves 4-7 = decoder (same rows). enc(t) and
// dec(t-1) are independent -> run concurrently on different waves; one block
// barrier per step; he staged in a DOUBLE-BUFFERED LDS region. Per-wave
// critical path halves (one cell/step, not enc->dec serial), and enc/dec
// waves present different instruction mixes at any instant (dec MFMA overlaps
// enc trans burst). Refuted so far: occupancy capacity (r14), loop-LDS
// latency (r13), NG=2 ILP (r11), stagger (r15) -- all null at ~96us with
// VALU busy pinned at ~59us aggregate.
// Frag table, k-mapping (k=g*8+e), bias at k=25 (A col 25 == 1.0), C/D layout
// (col=lane&15, row=(lane>>4)*4+q), store masks: byte-identical to r14.
// LDS = 24K frags + 16K he(2 buf) + 8K hd = 49152 B -> 3 blocks/CU.

#define HH 25
#define NSTEP 10
#define AOUT 18
#define BLK 512
#define NWENC 4
#define MT 2
#define NFRG 24   // 0..7 enc(Wih+Whh) | 8..15 decX | 16..23 decH
#define FPAD 32   // 64B row stride
#define LOG2E 1.44269504088896340736f

typedef __attribute__((ext_vector_type(8))) short short8;
typedef __attribute__((ext_vector_type(4))) float f32x4;

__device__ __forceinline__ short f2bf(float x) {   // f32 -> bf16 (RNE)
    unsigned u = __float_as_uint(x);
    u += 0x7fffu + ((u >> 16) & 1u);
    return (short)(u >> 16);
}
__device__ __forceinline__ unsigned cvtpk(float lo, float hi) {  // 2xf32 -> packed bf16
    unsigned rr;
    asm("v_cvt_pk_bf16_f32 %0, %1, %2" : "=v"(rr) : "v"(lo), "v"(hi));
    return rr;
}
#if __has_builtin(__builtin_amdgcn_exp2f)
#define EXP2(x) __builtin_amdgcn_exp2f(x)
#else
#define EXP2(x) exp2f(x)
#endif
#define RCP(x) __builtin_amdgcn_rcpf(x)
#define MFMA16(a, b, c) __builtin_amdgcn_mfma_f32_16x16x32_bf16((a), (b), (c), 0, 0, 0)

// one LSTM activation element: gates i,f,g,o pre-scaled by -log2e/+2log2e
#define ACT_ELEM(A0, A1, A2, A3, CREF, HOUT)                                   \
    {                                                                          \
        float Ei = EXP2(A0);                                                   \
        float Ef = EXP2(A1);                                                   \
        float Eg = EXP2(A2);                                                   \
        float Eo = EXP2(A3);                                                   \
        float Pf = 1.f + Ef;                                                   \
        float Pig = (1.f + Ei) * (1.f + Eg);                                   \
        float c = fmaf(CREF, Pig, (Eg - 1.f) * Pf) * RCP(Pf * Pig);            \
        CREF = c;                                                              \
        float Ec = EXP2(2.f * LOG2E * c);                                      \
        float Pc = 1.f + Ec;                                                   \
        HOUT = (Pc - 2.f) * RCP(Pc * (1.f + Eo));                              \
    }

__global__ __launch_bounds__(BLK, 4)
void langnn_ws(const float* __restrict__ state,
               const float* __restrict__ Wih_e, const float* __restrict__ Whh_e,
               const float* __restrict__ bih_e, const float* __restrict__ bhh_e,
               const float* __restrict__ Wih_d, const float* __restrict__ Whh_d,
               const float* __restrict__ bih_d, const float* __restrict__ bhh_d,
               const float* __restrict__ Wact, const float* __restrict__ bact,
               float* __restrict__ out, int B)
{
    __shared__ __align__(16) short sFrag[NFRG][64][8];      // 24 KB
    __shared__ __align__(16) short sHE[2][128][FPAD];       // 16 KB (he, dbl-buf)
    __shared__ __align__(16) short sHD[NWENC][32][FPAD];    //  8 KB (hd, per dec wave)

    const int tid  = threadIdx.x;
    const int lane = tid & 63;
    const int w    = tid >> 6;
    const int r    = lane & 15;    // A-row / C-col lane index
    const int g    = lane >> 4;    // k-group / C row-group

    // ---- build B-fragment table (bias folded into k=25 row) ----
    for (int i = tid; i < NFRG * 64; i += BLK) {
        const int idx = i >> 6, l = i & 63;
        const int lj = l & 15, lg = l >> 4;
        const float *W1 = nullptr, *W2 = nullptr, *B1 = nullptr, *B2 = nullptr;
        int gt, jt;
        if (idx < 8)       { gt = idx >> 1;        jt = idx & 1; W1 = Wih_e; W2 = Whh_e; B1 = bih_e; B2 = bhh_e; }
        else if (idx < 16) { gt = (idx - 8) >> 1;  jt = idx & 1; W1 = Wih_d; B1 = bih_d; B2 = bhh_d; }
        else               { gt = (idx - 16) >> 1; jt = idx & 1; W1 = Whh_d; }
        const float sc = (gt == 2 ? 2.f * LOG2E : -LOG2E);
        const int col = jt * 16 + lj;
        const int nrow = gt * HH + col;
        for (int e = 0; e < 8; ++e) {
            const int k = lg * 8 + e;
            float v = 0.f;
            if (col < HH) {
                if (k < HH) {
                    v = W1[nrow * HH + k];
                    if (W2) v += W2[nrow * HH + k];
                    v *= sc;
                } else if (k == HH && B1) {
                    v = B1[nrow];
                    if (B2) v += B2[nrow];
                    v *= sc;
                }
            }
            sFrag[idx][l][e] = f2bf(v);
        }
    }
    // ---- init staging: zeros, col 25 = 1.0 (bias lane of the A-fragment) ----
    {
        int* zE = (int*)sHE;
        for (int i = tid; i < 2 * 128 * (FPAD / 2); i += BLK)
            zE[i] = ((i % (FPAD / 2)) == 12) ? 0x3F800000 : 0;   // shorts 24|25 -> 0|1.0
        int* zD = (int*)sHD;
        for (int i = tid; i < NWENC * 32 * (FPAD / 2); i += BLK)
            zD[i] = ((i % (FPAD / 2)) == 12) ? 0x3F800000 : 0;
    }
    __syncthreads();

    const bool isEnc = (w < NWENC);
    const int wl = isEnc ? w : (w - NWENC);
    const int rowBase = wl * 32;                       // local row base (0..96)
    const int gBase = blockIdx.x * 128 + rowBase;      // global batch row base

    float cc[MT][2][4];   // ce (enc waves) / cd (dec waves)
    #pragma unroll
    for (int mt = 0; mt < MT; ++mt)
        #pragma unroll
        for (int jt = 0; jt < 2; ++jt)
            #pragma unroll
            for (int q = 0; q < 4; ++q) cc[mt][jt][q] = 0.f;

    short8 aE[MT], aD[MT];
    #pragma unroll
    for (int mt = 0; mt < MT; ++mt) {
        #pragma unroll
        for (int e = 0; e < 8; ++e) {
            const int k = g * 8 + e;
            aD[mt][e] = (k == HH) ? (short)0x3F80 : (short)0;   // hd(-1)=0 + bias lane
        }
    }
    if (isEnc) {
        #pragma unroll
        for (int mt = 0; mt < MT; ++mt) {
            const float* sp0 = state + (size_t)(gBase + mt * 16 + r) * HH;
            #pragma unroll
            for (int e = 0; e < 8; ++e) {
                const int k = g * 8 + e;
                aE[mt][e] = (k < HH) ? f2bf(sp0[k]) : (k == HH ? (short)0x3F80 : (short)0);
            }
        }
    }

    // ================= enc step 0 (enc waves; W_ih-only frags from global) ===
    if (isEnc) {
        #pragma unroll
        for (int jt = 0; jt < 2; ++jt) {
            f32x4 acc[MT][4];
            #pragma unroll
            for (int gt = 0; gt < 4; ++gt) {
                const float sc = (gt == 2) ? 2.f * LOG2E : -LOG2E;
                const int col = jt * 16 + r;
                short8 Wf;
                #pragma unroll
                for (int e = 0; e < 8; ++e) {
                    const int k = g * 8 + e;
                    float v = 0.f;
                    if (col < HH) {
                        if (k < HH)       v = Wih_e[(gt * HH + col) * HH + k] * sc;
                        else if (k == HH) v = (bih_e[gt * HH + col] + bhh_e[gt * HH + col]) * sc;
                    }
                    Wf[e] = f2bf(v);
                }
                f32x4 z; z[0] = z[1] = z[2] = z[3] = 0.f;
                #pragma unroll
                for (int mt = 0; mt < MT; ++mt) acc[mt][gt] = MFMA16(aE[mt], Wf, z);
            }
            #pragma unroll
            for (int mt = 0; mt < MT; ++mt) {
                float hv[4];
                #pragma unroll
                for (int q = 0; q < 4; ++q)
                    ACT_ELEM(acc[mt][0][q], acc[mt][1][q], acc[mt][2][q], acc[mt][3][q],
                             cc[mt][jt][q], hv[q]);
                if (jt == 0 || r < 9) {
                    float* p = out + (size_t)B * AOUT
                             + (size_t)(gBase + mt * 16 + g * 4) * HH + jt * 16 + r;
                    p[0] = hv[0]; p[HH] = hv[1]; p[2 * HH] = hv[2]; p[3 * HH] = hv[3];
                    unsigned p01 = cvtpk(hv[0], hv[1]), p23 = cvtpk(hv[2], hv[3]);
                    short* sp = &sHE[0][rowBase + mt * 16 + g * 4][jt * 16 + r];
                    sp[0]        = (short)p01;
                    sp[FPAD]     = (short)(p01 >> 16);
                    sp[2 * FPAD] = (short)p23;
                    sp[3 * FPAD] = (short)(p23 >> 16);
                }
            }
        }
        #pragma unroll
        for (int mt = 0; mt < MT; ++mt)
            aE[mt] = *(const short8*)&sHE[0][rowBase + mt * 16 + r][g * 8];
    }
    __syncthreads();   // he(0) visible to dec waves

    // ================= pipelined loop: enc(t) || dec(t-1) ====================
    #pragma unroll 1
    for (int t = 1; t < NSTEP; ++t) {
        if (isEnc) {
            const int buf = t & 1;
            #pragma unroll
            for (int jt = 0; jt < 2; ++jt) {
                f32x4 acc[MT][4];
                #pragma unroll
                for (int gt = 0; gt < 4; ++gt) {
                    short8 Bf = *(const short8*)&sFrag[gt * 2 + jt][lane][0];
                    f32x4 z; z[0] = z[1] = z[2] = z[3] = 0.f;
                    #pragma unroll
                    for (int mt = 0; mt < MT; ++mt) acc[mt][gt] = MFMA16(aE[mt], Bf, z);
                }
                #pragma unroll
                for (int mt = 0; mt < MT; ++mt) {
                    float hv[4];
                    #pragma unroll
                    for (int q = 0; q < 4; ++q)
                        ACT_ELEM(acc[mt][0][q], acc[mt][1][q], acc[mt][2][q], acc[mt][3][q],
                                 cc[mt][jt][q], hv[q]);
                    if (jt == 0 || r < 9) {
                        float* p = out + (size_t)B * AOUT + (size_t)t * B * HH
                                 + (size_t)(gBase + mt * 16 + g * 4) * HH + jt * 16 + r;
                        p[0] = hv[0]; p[HH] = hv[1]; p[2 * HH] = hv[2]; p[3 * HH] = hv[3];
                        unsigned p01 = cvtpk(hv[0], hv[1]), p23 = cvtpk(hv[2], hv[3]);
                        short* sp = &sHE[buf][rowBase + mt * 16 + g * 4][jt * 16 + r];
                        sp[0]        = (short)p01;
                        sp[FPAD]     = (short)(p01 >> 16);
                        sp[2 * FPAD] = (short)p23;
                        sp[3 * FPAD] = (short)(p23 >> 16);
                    }
                }
            }
            #pragma unroll
            for (int mt = 0; mt < MT; ++mt)
                aE[mt] = *(const short8*)&sHE[buf][rowBase + mt * 16 + r][g * 8];
        } else {
            const int buf = (t - 1) & 1;
            short8 aEd[MT];
            #pragma unroll
            for (int mt = 0; mt < MT; ++mt)
                aEd[mt] = *(const short8*)&sHE[buf][rowBase + mt * 16 + r][g * 8];
            #pragma unroll
            for (int jt = 0; jt < 2; ++jt) {
                f32x4 acc[MT][4];
                #pragma unroll
                for (int gt = 0; gt < 4; ++gt) {
                    short8 Bx = *(const short8*)&sFrag[8 + gt * 2 + jt][lane][0];
                    short8 Bh = *(const short8*)&sFrag[16 + gt * 2 + jt][lane][0];
                    f32x4 z; z[0] = z[1] = z[2] = z[3] = 0.f;
                    #pragma unroll
                    for (int mt = 0; mt < MT; ++mt)
                        acc[mt][gt] = MFMA16(aD[mt], Bh, MFMA16(aEd[mt], Bx, z));
                }
                #pragma unroll
                for (int mt = 0; mt < MT; ++mt) {
                    float hv[4];
                    #pragma unroll
                    for (int q = 0; q < 4; ++q)
                        ACT_ELEM(acc[mt][0][q], acc[mt][1][q], acc[mt][2][q], acc[mt][3][q],
                                 cc[mt][jt][q], hv[q]);
                    if (jt == 0 || r < 9) {
                        unsigned p01 = cvtpk(hv[0], hv[1]), p23 = cvtpk(hv[2], hv[3]);
                        short* sp = &sHD[wl][mt * 16 + g * 4][jt * 16 + r];
                        sp[0]        = (short)p01;
                        sp[FPAD]     = (short)(p01 >> 16);
                        sp[2 * FPAD] = (short)p23;
                        sp[3 * FPAD] = (short)(p23 >> 16);
                    }
                }
            }
            #pragma unroll
            for (int mt = 0; mt < MT; ++mt)
                aD[mt] = *(const short8*)&sHD[wl][mt * 16 + r][g * 8];
        }
        __syncthreads();
    }

    // ================= dec step 9 + actor head (dec waves only) ==============
    if (!isEnc) {
        short8 aEd[MT];
        #pragma unroll
        for (int mt = 0; mt < MT; ++mt)
            aEd[mt] = *(const short8*)&sHE[(NSTEP - 1) & 1][rowBase + mt * 16 + r][g * 8];
        #pragma unroll
        for (int jt = 0; jt < 2; ++jt) {
            f32x4 acc[MT][4];
            #pragma unroll
            for (int gt = 0; gt < 4; ++gt) {
                short8 Bx = *(const short8*)&sFrag[8 + gt * 2 + jt][lane][0];
                short8 Bh = *(const short8*)&sFrag[16 + gt * 2 + jt][lane][0];
                f32x4 z; z[0] = z[1] = z[2] = z[3] = 0.f;
                #pragma unroll
                for (int mt = 0; mt < MT; ++mt)
                    acc[mt][gt] = MFMA16(aD[mt], Bh, MFMA16(aEd[mt], Bx, z));
            }
            #pragma unroll
            for (int mt = 0; mt < MT; ++mt) {
                float hv[4];
                #pragma unroll
                for (int q = 0; q < 4; ++q)
                    ACT_ELEM(acc[mt][0][q], acc[mt][1][q], acc[mt][2][q], acc[mt][3][q],
                             cc[mt][jt][q], hv[q]);
                if (jt == 0 || r < 9) {
                    unsigned p01 = cvtpk(hv[0], hv[1]), p23 = cvtpk(hv[2], hv[3]);
                    short* sp = &sHD[wl][mt * 16 + g * 4][jt * 16 + r];
                    sp[0]        = (short)p01;
                    sp[FPAD]     = (short)(p01 >> 16);
                    sp[2 * FPAD] = (short)p23;
                    sp[3 * FPAD] = (short)(p23 >> 16);
                }
            }
        }
        #pragma unroll
        for (int mt = 0; mt < MT; ++mt)
            aD[mt] = *(const short8*)&sHD[wl][mt * 16 + r][g * 8];

        // actor head: frags built from global (epilogue-only; L2-hit)
        #pragma unroll
        for (int jt = 0; jt < 2; ++jt) {
            const int col = jt * 16 + r;
            short8 Bf;
            #pragma unroll
            for (int e = 0; e < 8; ++e) {
                const int k = g * 8 + e;
                float v = 0.f;
                if (col < AOUT) {
                    if (k < HH)       v = Wact[col * HH + k];
                    else if (k == HH) v = bact[col];
                }
                Bf[e] = f2bf(v);
            }
            f32x4 z; z[0] = z[1] = z[2] = z[3] = 0.f;
            #pragma unroll
            for (int mt = 0; mt < MT; ++mt) {
                f32x4 o = MFMA16(aD[mt], Bf, z);
                if (jt == 0 || r < 2) {
                    float* p = out + (size_t)(gBase + mt * 16 + g * 4) * AOUT + jt * 16 + r;
                    p[0] = o[0]; p[AOUT] = o[1]; p[2 * AOUT] = o[2]; p[3 * AOUT] = o[3];
                }
            }
        }
    }
}

extern "C" void kernel_launch(void* const* d_in, const int* in_sizes, int n_in,
                              void* d_out, int out_size, void* d_ws, size_t ws_size,
                              hipStream_t stream) {
    const float* state = (const float*)d_in[0];
    const float* Wih_e = (const float*)d_in[1];
    const float* Whh_e = (const float*)d_in[2];
    const float* bih_e = (const float*)d_in[3];
    const float* bhh_e = (const float*)d_in[4];
    const float* Wih_d = (const float*)d_in[5];
    const float* Whh_d = (const float*)d_in[6];
    const float* bih_d = (const float*)d_in[7];
    const float* bhh_d = (const float*)d_in[8];
    const float* Wact  = (const float*)d_in[9];
    const float* bact  = (const float*)d_in[10];

    int B = in_sizes[0] / HH;
    int grid = B / 128;   // 1024 blocks, 128 batch rows each

    hipLaunchKernelGGL(langnn_ws, dim3(grid), dim3(BLK), 0, stream,
                       state, Wih_e, Whh_e, bih_e, bhh_e,
                       Wih_d, Whh_d, bih_d, bhh_d, Wact, bact,
                       (float*)d_out, B);
}